// Round 1
// baseline (4015.781 us; speedup 1.0000x reference)
//
#include <hip/hip_runtime.h>
#include <hip/hip_bf16.h>
#include <stdint.h>

#define BATCH 16
#define SEQ   2048
#define CH    1024
#define NH    16
#define NG    4
#define KW    5
#define GCH   256
#define DHD   64
#define NBG   (BATCH*NG)   // 64
#define NBH   (BATCH*NH)   // 256
#define MROWS (BATCH*SEQ)  // 32768

typedef __hip_bfloat16 bf16;

__device__ __forceinline__ void unpack8(uint4 r, float* f){
    uint32_t w0=r.x,w1=r.y,w2=r.z,w3=r.w;
    f[0]=__uint_as_float(w0<<16); f[1]=__uint_as_float(w0&0xffff0000u);
    f[2]=__uint_as_float(w1<<16); f[3]=__uint_as_float(w1&0xffff0000u);
    f[4]=__uint_as_float(w2<<16); f[5]=__uint_as_float(w2&0xffff0000u);
    f[6]=__uint_as_float(w3<<16); f[7]=__uint_as_float(w3&0xffff0000u);
}
__device__ __forceinline__ void unpack4(uint2 r, float* f){
    f[0]=__uint_as_float(r.x<<16); f[1]=__uint_as_float(r.x&0xffff0000u);
    f[2]=__uint_as_float(r.y<<16); f[3]=__uint_as_float(r.y&0xffff0000u);
}

// ---------------------------------------------------------------------------
// Weff[kk][cj] = sum_co w2[co] * W1[co][cj][kk];  wconst = {b2, dot(w2,b1)}
// (conv2 o conv1 is linear before tanh -> collapse to one 5x256 filter)
// ---------------------------------------------------------------------------
__global__ void prep_weff_kernel(const float* __restrict__ W1, const float* __restrict__ b1,
                                 const float* __restrict__ w2, const float* __restrict__ b2,
                                 float* __restrict__ weff, float* __restrict__ wcst)
{
    int kk = blockIdx.x;          // 0..4
    int cj = threadIdx.x;         // 0..255
    float s = 0.f;
    for (int co=0; co<GCH; ++co)
        s += w2[co] * W1[((size_t)co*GCH + cj)*KW + kk];
    weff[kk*GCH + cj] = s;
    if (kk==0 && cj==0){
        float sb = 0.f;
        for (int co=0; co<GCH; ++co) sb += w2[co]*b1[co];
        wcst[0] = b2[0];
        wcst[1] = sb;
    }
}

// ---------------------------------------------------------------------------
// GEMM: C[m][n] = sum_k A[m][k]*W[n][k] + bias[n] (+ rpb[n][m%SEQ])
// A: [MROWS][CH] (fp32 or bf16), W: [CH][CH] fp32 row-major ([n][k]).
// 128x128 tile, BK=16, 256 threads, 8x8 per thread, fp32 accumulate.
// ---------------------------------------------------------------------------
template<typename AT, typename OT, bool ADD_RPB>
__global__ __launch_bounds__(256)
void gemm_bt_kernel(const AT* __restrict__ A, const float* __restrict__ W,
                    const float* __restrict__ bias, const float* __restrict__ rpb,
                    OT* __restrict__ Cout)
{
    __shared__ float As[16][136];
    __shared__ float Ws[16][136];
    const int t  = threadIdx.x;
    const int m0 = blockIdx.y*128, n0 = blockIdx.x*128;
    const int tx = t & 15, ty = t >> 4;
    const int lr = t >> 1;        // 0..127
    const int lk = (t & 1)*8;     // 0 or 8

    float acc[8][8];
    #pragma unroll
    for (int i=0;i<8;++i)
        #pragma unroll
        for (int j=0;j<8;++j) acc[i][j]=0.f;

    const AT*    aBase = A + (size_t)(m0+lr)*CH + lk;
    const float* wBase = W + (size_t)(n0+lr)*CH + lk;

    for (int kc=0; kc<CH; kc+=16){
        float av[8];
        if constexpr (sizeof(AT)==2){
            uint4 r = *(const uint4*)(aBase + kc);
            unpack8(r, av);
        } else {
            float4 f0 = *(const float4*)(aBase + kc);
            float4 f1 = *(const float4*)(aBase + kc + 4);
            av[0]=f0.x;av[1]=f0.y;av[2]=f0.z;av[3]=f0.w;
            av[4]=f1.x;av[5]=f1.y;av[6]=f1.z;av[7]=f1.w;
        }
        float4 w0 = *(const float4*)(wBase + kc);
        float4 w1 = *(const float4*)(wBase + kc + 4);
        #pragma unroll
        for (int j=0;j<8;++j) As[lk+j][lr] = av[j];
        Ws[lk+0][lr]=w0.x; Ws[lk+1][lr]=w0.y; Ws[lk+2][lr]=w0.z; Ws[lk+3][lr]=w0.w;
        Ws[lk+4][lr]=w1.x; Ws[lk+5][lr]=w1.y; Ws[lk+6][lr]=w1.z; Ws[lk+7][lr]=w1.w;
        __syncthreads();
        #pragma unroll
        for (int kk=0;kk<16;++kk){
            float a[8], b[8];
            *(float4*)&a[0] = *(const float4*)&As[kk][ty*8];
            *(float4*)&a[4] = *(const float4*)&As[kk][ty*8+4];
            *(float4*)&b[0] = *(const float4*)&Ws[kk][tx*8];
            *(float4*)&b[4] = *(const float4*)&Ws[kk][tx*8+4];
            #pragma unroll
            for (int i=0;i<8;++i)
                #pragma unroll
                for (int j=0;j<8;++j) acc[i][j] += a[i]*b[j];
        }
        __syncthreads();
    }

    #pragma unroll
    for (int i=0;i<8;++i){
        int m = m0 + ty*8 + i;
        int l = m & (SEQ-1);
        if constexpr (sizeof(OT)==2){
            union { bf16 b[8]; uint4 u; } pk;
            #pragma unroll
            for (int j=0;j<8;++j){
                int n = n0 + tx*8 + j;
                float v = acc[i][j] + bias[n];
                if constexpr (ADD_RPB) v += rpb[(size_t)n*SEQ + l];
                pk.b[j] = __float2bfloat16(v);
            }
            *(uint4*)((bf16*)Cout + (size_t)m*CH + n0 + tx*8) = pk.u;
        } else {
            float of[8];
            #pragma unroll
            for (int j=0;j<8;++j){
                int n = n0 + tx*8 + j;
                float v = acc[i][j] + bias[n];
                if constexpr (ADD_RPB) v += rpb[(size_t)n*SEQ + l];
                of[j] = v;
            }
            *(float4*)((float*)Cout + (size_t)m*CH + n0 + tx*8) = *(float4*)&of[0];
            *(float4*)((float*)Cout + (size_t)m*CH + n0 + tx*8 + 4) = *(float4*)&of[4];
        }
    }
}

// ---------------------------------------------------------------------------
// P5[bg][row][kk] = dot(Weff[kk][:], Q[b][row][g*256:(g+1)*256])  (one wave/row)
// ---------------------------------------------------------------------------
__global__ __launch_bounds__(256)
void pdots_kernel(const bf16* __restrict__ Q, const float* __restrict__ weff,
                  float* __restrict__ P5)
{
    int wave = threadIdx.x >> 6, lane = threadIdx.x & 63;
    int row  = blockIdx.x*4 + wave;   // 0..SEQ-1
    int bg   = blockIdx.y;            // 0..63
    int b = bg >> 2, g = bg & 3;
    const bf16* qp = Q + ((size_t)(b*SEQ + row))*CH + g*GCH + lane*4;
    uint2 raw = *(const uint2*)qp;
    float qv[4]; unpack4(raw, qv);
    float acc[KW];
    #pragma unroll
    for (int kk=0;kk<KW;++kk){
        float4 w = *(const float4*)(weff + kk*GCH + lane*4);
        acc[kk] = qv[0]*w.x + qv[1]*w.y + qv[2]*w.z + qv[3]*w.w;
    }
    #pragma unroll
    for (int m=32;m;m>>=1){
        #pragma unroll
        for (int kk=0;kk<KW;++kk) acc[kk] += __shfl_xor(acc[kk], m);
    }
    if (lane==0){
        #pragma unroll
        for (int kk=0;kk<KW;++kk)
            P5[((size_t)bg*SEQ + row)*KW + kk] = acc[kk];
    }
}

// ---------------------------------------------------------------------------
// off -> tanh -> sampling position (pos = (l'+off)*2048/2051 - 0.5)
// ---------------------------------------------------------------------------
__global__ __launch_bounds__(256)
void pos_kernel(const float* __restrict__ P5, const float* __restrict__ wcst,
                float* __restrict__ posb)
{
    int lp = blockIdx.x*256 + threadIdx.x;   // l'
    int bg = blockIdx.y;
    float b2 = wcst[0], wb1 = wcst[1];
    float o;
    if (lp < 2){
        o = b2;                 // conv2 pad region: h contributes nothing
    } else {
        float s = b2 + wb1;
        #pragma unroll
        for (int kk=0;kk<KW;++kk){
            int jj = lp - 4 + kk;
            if (jj >= 0 && jj < SEQ) s += P5[((size_t)bg*SEQ + jj)*KW + kk];
        }
        o = s;
    }
    float off = tanhf(o) * (float)KW;
    posb[bg*SEQ + lp] = ((float)lp + off) * (2048.0f/2051.0f) - 0.5f;
}

// ---------------------------------------------------------------------------
// bilinear zero-pad sampler: XS[b][l'][g*256+ci]
// ---------------------------------------------------------------------------
__global__ __launch_bounds__(256)
void sample_kernel(const float* __restrict__ x, const float* __restrict__ posb,
                   bf16* __restrict__ XS)
{
    int lp = blockIdx.x, bg = blockIdx.y, ci = threadIdx.x;
    int b = bg >> 2, g = bg & 3;
    float p  = posb[bg*SEQ + lp];
    float fl = floorf(p);
    float w1 = p - fl;
    int i0 = (int)fl;
    float v = 0.f;
    if (i0 >= 0 && i0 < SEQ)
        v += x[((size_t)(b*SEQ + i0))*CH + g*GCH + ci] * (1.f - w1);
    if (i0+1 >= 0 && i0+1 < SEQ)
        v += x[((size_t)(b*SEQ + i0 + 1))*CH + g*GCH + ci] * w1;
    XS[((size_t)(b*SEQ + lp))*CH + g*GCH + ci] = __float2bfloat16(v);
}

// ---------------------------------------------------------------------------
// attention per (b,h): S = Qh^T Kh / 32 (64x64 over L=2048), softmax rows,
// F[b][l][h*64+i] = sum_j P[i][j] * V[b][l][h*64+j]
// ---------------------------------------------------------------------------
__global__ __launch_bounds__(256)
void attn_kernel(const bf16* __restrict__ Q, const bf16* __restrict__ Kb,
                 const bf16* __restrict__ Vb, bf16* __restrict__ F)
{
    __shared__ float Sc[64][68];
    __shared__ float Qc[32][68];
    __shared__ float Kc[32][68];
    __shared__ float Vw[4][16][68];
    const int t = threadIdx.x;
    const int bh = blockIdx.x;
    const int b = bh >> 4, h = bh & 15;
    const size_t base = (size_t)b*SEQ*CH + (size_t)h*DHD;

    float acc[4][4];
    #pragma unroll
    for (int i=0;i<4;++i)
        #pragma unroll
        for (int j=0;j<4;++j) acc[i][j]=0.f;

    const int ib = (t & 15)*4, jb = (t >> 4)*4;
    const int sr = t >> 3,  sc = (t & 7)*8;

    for (int c0=0; c0<SEQ; c0+=32){
        uint4 qr = *(const uint4*)(Q  + base + (size_t)(c0+sr)*CH + sc);
        uint4 kr = *(const uint4*)(Kb + base + (size_t)(c0+sr)*CH + sc);
        float qf[8], kf[8];
        unpack8(qr, qf); unpack8(kr, kf);
        #pragma unroll
        for (int j=0;j<8;++j){ Qc[sr][sc+j]=qf[j]; Kc[sr][sc+j]=kf[j]; }
        __syncthreads();
        #pragma unroll
        for (int rr=0;rr<32;++rr){
            float4 qa = *(const float4*)&Qc[rr][ib];
            float4 ka = *(const float4*)&Kc[rr][jb];
            float aa[4]={qa.x,qa.y,qa.z,qa.w};
            float bb[4]={ka.x,ka.y,ka.z,ka.w};
            #pragma unroll
            for (int i=0;i<4;++i)
                #pragma unroll
                for (int j=0;j<4;++j) acc[i][j] += aa[i]*bb[j];
        }
        __syncthreads();
    }
    #pragma unroll
    for (int i=0;i<4;++i)
        #pragma unroll
        for (int j=0;j<4;++j) Sc[ib+i][jb+j] = acc[i][j]*0.03125f;
    __syncthreads();

    if (t < 64){
        float mx = -1e30f;
        for (int j=0;j<64;++j) mx = fmaxf(mx, Sc[t][j]);
        float s = 0.f;
        for (int j=0;j<64;++j){ float e = expf(Sc[t][j]-mx); Sc[t][j]=e; s+=e; }
        float inv = 1.f/s;
        for (int j=0;j<64;++j) Sc[t][j] *= inv;
    }
    __syncthreads();

    const int wave = t >> 6, lane = t & 63;
    float4 p[16];
    #pragma unroll
    for (int q4=0;q4<16;++q4) p[q4] = *(const float4*)&Sc[lane][q4*4];

    const int vr = lane >> 2, vc = (lane & 3)*16;
    for (int it=0; it<32; ++it){
        int c0 = wave*512 + it*16;
        const bf16* vrow = Vb + base + (size_t)(c0+vr)*CH + vc;
        uint4 v0 = *(const uint4*)vrow;
        uint4 v1 = *(const uint4*)(vrow + 8);
        float vf[8], vg[8];
        unpack8(v0, vf); unpack8(v1, vg);
        #pragma unroll
        for (int j=0;j<8;++j){ Vw[wave][vr][vc+j]=vf[j]; Vw[wave][vr][vc+8+j]=vg[j]; }
        __syncthreads();
        #pragma unroll
        for (int r2=0;r2<16;++r2){
            float s = 0.f;
            #pragma unroll
            for (int q4=0;q4<16;++q4){
                float4 v4 = *(const float4*)&Vw[wave][r2][q4*4];
                s += p[q4].x*v4.x + p[q4].y*v4.y + p[q4].z*v4.z + p[q4].w*v4.w;
            }
            F[base + (size_t)(c0+r2)*CH + lane] = __float2bfloat16(s);
        }
        __syncthreads();
    }
}

// ---------------------------------------------------------------------------
extern "C" void kernel_launch(void* const* d_in, const int* in_sizes, int n_in,
                              void* d_out, int out_size, void* d_ws, size_t ws_size,
                              hipStream_t stream)
{
    const float* x   = (const float*)d_in[0];
    const float* Wq  = (const float*)d_in[1];
    const float* bq  = (const float*)d_in[2];
    const float* Wk  = (const float*)d_in[3];
    const float* bk  = (const float*)d_in[4];
    const float* Wv  = (const float*)d_in[5];
    const float* bv  = (const float*)d_in[6];
    const float* W1  = (const float*)d_in[7];
    const float* b1  = (const float*)d_in[8];
    const float* w2  = (const float*)d_in[9];
    const float* b2  = (const float*)d_in[10];
    const float* rpb = (const float*)d_in[11];
    const float* Wo  = (const float*)d_in[12];
    const float* bo  = (const float*)d_in[13];

    char* ws = (char*)d_ws;
    bf16*  Qb   = (bf16*)(ws);                          // 64 MiB
    bf16*  XS   = (bf16*)(ws + (size_t)67108864);       // 64 MiB (reused as F)
    bf16*  KB   = (bf16*)(ws + (size_t)134217728);      // 64 MiB
    bf16*  VB   = (bf16*)(ws + (size_t)201326592);      // 64 MiB
    float* posb = (float*)(ws + (size_t)268435456);     // 512 KiB
    float* P5   = (float*)(ws + (size_t)268959744);     // 2.5 MiB
    float* weff = (float*)(ws + (size_t)271581184);     // 5 KiB
    float* wcst = (float*)(ws + (size_t)271586304);     // 8 B
    bf16*  Fb   = XS;

    prep_weff_kernel<<<dim3(KW), dim3(GCH), 0, stream>>>(W1, b1, w2, b2, weff, wcst);
    gemm_bt_kernel<float,bf16,false><<<dim3(8,256), 256, 0, stream>>>(x,  Wq, bq, nullptr, Qb);
    pdots_kernel<<<dim3(SEQ/4, NBG), 256, 0, stream>>>(Qb, weff, P5);
    pos_kernel<<<dim3(SEQ/256, NBG), 256, 0, stream>>>(P5, wcst, posb);
    sample_kernel<<<dim3(SEQ, NBG), 256, 0, stream>>>(x, posb, XS);
    gemm_bt_kernel<bf16,bf16,false><<<dim3(8,256), 256, 0, stream>>>(XS, Wk, bk, nullptr, KB);
    gemm_bt_kernel<bf16,bf16,true ><<<dim3(8,256), 256, 0, stream>>>(XS, Wv, bv, rpb,    VB);
    attn_kernel<<<dim3(NBH), 256, 0, stream>>>(Qb, KB, VB, Fb);
    gemm_bt_kernel<bf16,float,false><<<dim3(8,256), 256, 0, stream>>>(Fb, Wo, bo, nullptr, (float*)d_out);
}

// Round 2
// 1126.632 us; speedup vs baseline: 3.5644x; 3.5644x over previous
//
#include <hip/hip_runtime.h>
#include <hip/hip_bf16.h>
#include <stdint.h>

#define BATCH 16
#define SEQ   2048
#define CH    1024
#define NH    16
#define NG    4
#define KW    5
#define GCH   256
#define DHD   64
#define NBG   (BATCH*NG)   // 64
#define NBH   (BATCH*NH)   // 256
#define MROWS (BATCH*SEQ)  // 32768

#define BM 128
#define BN 128
#define BK 64

typedef __hip_bfloat16 bf16;
typedef float f32x4 __attribute__((ext_vector_type(4)));
typedef __bf16 bf16x8 __attribute__((ext_vector_type(8)));

__device__ __forceinline__ void unpack8(uint4 r, float* f){
    uint32_t w0=r.x,w1=r.y,w2=r.z,w3=r.w;
    f[0]=__uint_as_float(w0<<16); f[1]=__uint_as_float(w0&0xffff0000u);
    f[2]=__uint_as_float(w1<<16); f[3]=__uint_as_float(w1&0xffff0000u);
    f[4]=__uint_as_float(w2<<16); f[5]=__uint_as_float(w2&0xffff0000u);
    f[6]=__uint_as_float(w3<<16); f[7]=__uint_as_float(w3&0xffff0000u);
}
__device__ __forceinline__ void unpack4(uint2 r, float* f){
    f[0]=__uint_as_float(r.x<<16); f[1]=__uint_as_float(r.x&0xffff0000u);
    f[2]=__uint_as_float(r.y<<16); f[3]=__uint_as_float(r.y&0xffff0000u);
}

// ---------------------------------------------------------------------------
// fp32 -> bf16 convert, 8 elems/thread
// ---------------------------------------------------------------------------
__global__ __launch_bounds__(256)
void cvt_kernel(const float* __restrict__ in, bf16* __restrict__ out, int n)
{
    int i = (blockIdx.x*256 + threadIdx.x)*8;
    if (i >= n) return;
    float4 f0 = *(const float4*)(in+i);
    float4 f1 = *(const float4*)(in+i+4);
    union { bf16 b[8]; uint4 u; } pk;
    pk.b[0]=__float2bfloat16(f0.x); pk.b[1]=__float2bfloat16(f0.y);
    pk.b[2]=__float2bfloat16(f0.z); pk.b[3]=__float2bfloat16(f0.w);
    pk.b[4]=__float2bfloat16(f1.x); pk.b[5]=__float2bfloat16(f1.y);
    pk.b[6]=__float2bfloat16(f1.z); pk.b[7]=__float2bfloat16(f1.w);
    *(uint4*)(out+i) = pk.u;
}

// ---------------------------------------------------------------------------
// Weff[kk][cj] = sum_co w2[co] * W1[co][cj][kk];  wcst = {b2, dot(w2,b1)}
// ---------------------------------------------------------------------------
__global__ void prep_weff_kernel(const float* __restrict__ W1, const float* __restrict__ b1,
                                 const float* __restrict__ w2, const float* __restrict__ b2,
                                 float* __restrict__ weff, float* __restrict__ wcst)
{
    int kk = blockIdx.x;          // 0..4
    int cj = threadIdx.x;         // 0..255
    float s = 0.f;
    for (int co=0; co<GCH; ++co)
        s += w2[co] * W1[((size_t)co*GCH + cj)*KW + kk];
    weff[kk*GCH + cj] = s;
    if (kk==0 && cj==0){
        float sb = 0.f;
        for (int co=0; co<GCH; ++co) sb += w2[co]*b1[co];
        wcst[0] = b2[0];
        wcst[1] = sb;
    }
}

// ---------------------------------------------------------------------------
// MFMA GEMM (m97 structure): C[m][n] = sum_k A[m][k]*W[n][k] + bias[n] (+rpb)
// A: [MROWS][CH] bf16, W: [CH][CH] bf16 row-major [n][k].
// 128x128 tile, BK=64, 4 waves -> 64x64/wave, 16x16x32 MFMA, 4x4 frags.
// global_load_lds width=16, linear LDS, single-buffered 2-barrier loop.
// ---------------------------------------------------------------------------
template<bool ADD_RPB, typename OT>
__global__ __launch_bounds__(256)
void gemm_mfma_kernel(const bf16* __restrict__ A, const bf16* __restrict__ Wb,
                      const float* __restrict__ bias, const float* __restrict__ rpb,
                      OT* __restrict__ Cout)
{
    __shared__ __bf16 As[BM*BK];   // [128][64] row-major, 16 KiB
    __shared__ __bf16 Bs[BN*BK];
    const int t = threadIdx.x;
    const int w = t>>6, l = t&63;
    const int m0 = blockIdx.y*BM, n0 = blockIdx.x*BN;
    const int wr = w>>1, wc = w&1;        // wave -> 64x64 sub-tile
    const int lr = l&15;                  // frag row (A) / col (B)
    const int lk = (l>>4)*8;              // frag k elem offset

    f32x4 acc[4][4];
    #pragma unroll
    for (int i=0;i<4;++i)
        #pragma unroll
        for (int j=0;j<4;++j) acc[i][j] = (f32x4){0.f,0.f,0.f,0.f};

    const int srow = w*8 + (l>>3);        // staging row within 32-row chunk
    const int scol = (l&7)*8;             // staging k elem offset
    const bf16* Ag = A  + (size_t)m0*CH;
    const bf16* Bg = Wb + (size_t)n0*CH;

    for (int kt=0; kt<CH; kt+=BK){
        #pragma unroll
        for (int it=0; it<4; ++it){
            int row = it*32 + srow;
            // LDS dest: wave-uniform base; HW writes lane l at base + l*16B,
            // which is exactly row-major [row][64] linear order here.
            __builtin_amdgcn_global_load_lds(
                (const __attribute__((address_space(1))) void*)(Ag + (size_t)row*CH + kt + scol),
                (__attribute__((address_space(3))) void*)(As + (it*32 + w*8)*BK),
                16, 0, 0);
            __builtin_amdgcn_global_load_lds(
                (const __attribute__((address_space(1))) void*)(Bg + (size_t)row*CH + kt + scol),
                (__attribute__((address_space(3))) void*)(Bs + (it*32 + w*8)*BK),
                16, 0, 0);
        }
        __syncthreads();
        #pragma unroll
        for (int ks=0; ks<2; ++ks){
            bf16x8 af[4], bw[4];
            #pragma unroll
            for (int i=0;i<4;++i){
                af[i] = *(const bf16x8*)(As + (wr*64 + i*16 + lr)*BK + ks*32 + lk);
                bw[i] = *(const bf16x8*)(Bs + (wc*64 + i*16 + lr)*BK + ks*32 + lk);
            }
            #pragma unroll
            for (int i=0;i<4;++i)
                #pragma unroll
                for (int j=0;j<4;++j)
                    acc[i][j] = __builtin_amdgcn_mfma_f32_16x16x32_bf16(af[i], bw[j], acc[i][j], 0,0,0);
        }
        __syncthreads();
    }

    // epilogue: D[row=(l>>4)*4+r][col=l&15] per fragment (m89-verified layout)
    float bs[4];
    #pragma unroll
    for (int j=0;j<4;++j) bs[j] = bias[n0 + wc*64 + j*16 + lr];
    #pragma unroll
    for (int i=0;i<4;++i){
        #pragma unroll
        for (int r=0;r<4;++r){
            int mg = m0 + wr*64 + i*16 + (l>>4)*4 + r;
            int lseq = mg & (SEQ-1);
            #pragma unroll
            for (int j=0;j<4;++j){
                int ng = n0 + wc*64 + j*16 + lr;
                float v = acc[i][j][r] + bs[j];
                if constexpr (ADD_RPB) v += rpb[(size_t)ng*SEQ + lseq];
                if constexpr (sizeof(OT)==2)
                    ((bf16*)Cout)[(size_t)mg*CH + ng] = __float2bfloat16(v);
                else
                    ((float*)Cout)[(size_t)mg*CH + ng] = v;
            }
        }
    }
}

// ---------------------------------------------------------------------------
// fused offset network: per (bg, 256-row chunk): P5 rows in LDS, then
// off -> tanh -> sampling position posb = (l'+off)*2048/2051 - 0.5
// ---------------------------------------------------------------------------
__global__ __launch_bounds__(256)
void offsets_kernel(const bf16* __restrict__ Q, const float* __restrict__ weff,
                    const float* __restrict__ wcst, float* __restrict__ posb)
{
    __shared__ float P5L[264][5];
    const int t = threadIdx.x;
    const int w = t>>6, l = t&63;
    const int chunk = blockIdx.x;     // 0..7
    const int bg = blockIdx.y;        // 0..63
    const int b = bg>>2, g = bg&3;
    const int start = chunk*256;

    float wv[KW][4];
    #pragma unroll
    for (int kk=0;kk<KW;++kk){
        float4 w4 = *(const float4*)(weff + kk*GCH + l*4);
        wv[kk][0]=w4.x; wv[kk][1]=w4.y; wv[kk][2]=w4.z; wv[kk][3]=w4.w;
    }
    for (int idx = w; idx < 260; idx += 4){
        int j = start - 4 + idx;
        float acc[KW] = {0.f,0.f,0.f,0.f,0.f};
        if (j >= 0 && j < SEQ){
            const bf16* qp = Q + ((size_t)(b*SEQ + j))*CH + g*GCH + l*4;
            uint2 raw = *(const uint2*)qp;
            float qv[4]; unpack4(raw, qv);
            #pragma unroll
            for (int kk=0;kk<KW;++kk)
                acc[kk] = qv[0]*wv[kk][0]+qv[1]*wv[kk][1]+qv[2]*wv[kk][2]+qv[3]*wv[kk][3];
        }
        #pragma unroll
        for (int m=32;m;m>>=1){
            #pragma unroll
            for (int kk=0;kk<KW;++kk) acc[kk] += __shfl_xor(acc[kk], m);
        }
        if (l==0){
            P5L[idx][0]=acc[0]; P5L[idx][1]=acc[1]; P5L[idx][2]=acc[2];
            P5L[idx][3]=acc[3]; P5L[idx][4]=acc[4];
        }
    }
    __syncthreads();

    int lp = start + t;
    float b2 = wcst[0], wb1 = wcst[1];
    float o;
    if (lp < 2){
        o = b2;
    } else {
        float s = b2 + wb1;
        #pragma unroll
        for (int kk=0;kk<KW;++kk){
            int j = lp - 4 + kk;
            if (j >= 0 && j < SEQ) s += P5L[t+kk][kk];
        }
        o = s;
    }
    float off = tanhf(o) * (float)KW;
    posb[bg*SEQ + lp] = ((float)lp + off) * (2048.0f/2051.0f) - 0.5f;
}

// ---------------------------------------------------------------------------
// bilinear zero-pad sampler: XS[b][l'][g*256+ci]
// ---------------------------------------------------------------------------
__global__ __launch_bounds__(256)
void sample_kernel(const float* __restrict__ x, const float* __restrict__ posb,
                   bf16* __restrict__ XS)
{
    int lp = blockIdx.x, bg = blockIdx.y, ci = threadIdx.x;
    int b = bg >> 2, g = bg & 3;
    float p  = posb[bg*SEQ + lp];
    float fl = floorf(p);
    float w1 = p - fl;
    int i0 = (int)fl;
    float v = 0.f;
    if (i0 >= 0 && i0 < SEQ)
        v += x[((size_t)(b*SEQ + i0))*CH + g*GCH + ci] * (1.f - w1);
    if (i0+1 >= 0 && i0+1 < SEQ)
        v += x[((size_t)(b*SEQ + i0 + 1))*CH + g*GCH + ci] * w1;
    XS[((size_t)(b*SEQ + lp))*CH + g*GCH + ci] = __float2bfloat16(v);
}

// ---------------------------------------------------------------------------
// attention per (b,h): S = Qh Kh^T over L (64x64), softmax rows, F = P*V
// ---------------------------------------------------------------------------
__global__ __launch_bounds__(256)
void attn_kernel(const bf16* __restrict__ Q, const bf16* __restrict__ Kb,
                 const bf16* __restrict__ Vb, bf16* __restrict__ F)
{
    __shared__ float Sc[64][68];
    __shared__ float Qc[32][68];
    __shared__ float Kc[32][68];
    __shared__ float Vw[4][16][68];
    const int t = threadIdx.x;
    const int bh = blockIdx.x;
    const int b = bh >> 4, h = bh & 15;
    const size_t base = (size_t)b*SEQ*CH + (size_t)h*DHD;

    float acc[4][4];
    #pragma unroll
    for (int i=0;i<4;++i)
        #pragma unroll
        for (int j=0;j<4;++j) acc[i][j]=0.f;

    const int ib = (t & 15)*4, jb = (t >> 4)*4;
    const int sr = t >> 3,  sc = (t & 7)*8;

    for (int c0=0; c0<SEQ; c0+=32){
        uint4 qr = *(const uint4*)(Q  + base + (size_t)(c0+sr)*CH + sc);
        uint4 kr = *(const uint4*)(Kb + base + (size_t)(c0+sr)*CH + sc);
        float qf[8], kf[8];
        unpack8(qr, qf); unpack8(kr, kf);
        #pragma unroll
        for (int j=0;j<8;++j){ Qc[sr][sc+j]=qf[j]; Kc[sr][sc+j]=kf[j]; }
        __syncthreads();
        #pragma unroll
        for (int rr=0;rr<32;++rr){
            float4 qa = *(const float4*)&Qc[rr][ib];
            float4 ka = *(const float4*)&Kc[rr][jb];
            float aa[4]={qa.x,qa.y,qa.z,qa.w};
            float bb[4]={ka.x,ka.y,ka.z,ka.w};
            #pragma unroll
            for (int i=0;i<4;++i)
                #pragma unroll
                for (int j=0;j<4;++j) acc[i][j] += aa[i]*bb[j];
        }
        __syncthreads();
    }
    #pragma unroll
    for (int i=0;i<4;++i)
        #pragma unroll
        for (int j=0;j<4;++j) Sc[ib+i][jb+j] = acc[i][j]*0.03125f;
    __syncthreads();

    if (t < 64){
        float mx = -1e30f;
        for (int j=0;j<64;++j) mx = fmaxf(mx, Sc[t][j]);
        float s = 0.f;
        for (int j=0;j<64;++j){ float e = expf(Sc[t][j]-mx); Sc[t][j]=e; s+=e; }
        float inv = 1.f/s;
        for (int j=0;j<64;++j) Sc[t][j] *= inv;
    }
    __syncthreads();

    const int wave = t >> 6, lane = t & 63;
    float4 p[16];
    #pragma unroll
    for (int q4=0;q4<16;++q4) p[q4] = *(const float4*)&Sc[lane][q4*4];

    const int vr = lane >> 2, vc = (lane & 3)*16;
    for (int it=0; it<32; ++it){
        int c0 = wave*512 + it*16;
        const bf16* vrow = Vb + base + (size_t)(c0+vr)*CH + vc;
        uint4 v0 = *(const uint4*)vrow;
        uint4 v1 = *(const uint4*)(vrow + 8);
        float vf[8], vg[8];
        unpack8(v0, vf); unpack8(v1, vg);
        #pragma unroll
        for (int j=0;j<8;++j){ Vw[wave][vr][vc+j]=vf[j]; Vw[wave][vr][vc+8+j]=vg[j]; }
        __syncthreads();
        #pragma unroll
        for (int r2=0;r2<16;++r2){
            float s = 0.f;
            #pragma unroll
            for (int q4=0;q4<16;++q4){
                float4 v4 = *(const float4*)&Vw[wave][r2][q4*4];
                s += p[q4].x*v4.x + p[q4].y*v4.y + p[q4].z*v4.z + p[q4].w*v4.w;
            }
            F[base + (size_t)(c0+r2)*CH + lane] = __float2bfloat16(s);
        }
        __syncthreads();
    }
}

// ---------------------------------------------------------------------------
extern "C" void kernel_launch(void* const* d_in, const int* in_sizes, int n_in,
                              void* d_out, int out_size, void* d_ws, size_t ws_size,
                              hipStream_t stream)
{
    const float* x   = (const float*)d_in[0];
    const float* Wq  = (const float*)d_in[1];
    const float* bq  = (const float*)d_in[2];
    const float* Wk  = (const float*)d_in[3];
    const float* bk  = (const float*)d_in[4];
    const float* Wv  = (const float*)d_in[5];
    const float* bv  = (const float*)d_in[6];
    const float* W1  = (const float*)d_in[7];
    const float* b1  = (const float*)d_in[8];
    const float* w2  = (const float*)d_in[9];
    const float* b2  = (const float*)d_in[10];
    const float* rpb = (const float*)d_in[11];
    const float* Wo  = (const float*)d_in[12];
    const float* bo  = (const float*)d_in[13];

    char* ws = (char*)d_ws;
    bf16*  buf0 = (bf16*)(ws);                          // Xbf, later KB
    bf16*  Qb   = (bf16*)(ws + (size_t) 67108864);
    bf16*  XS   = (bf16*)(ws + (size_t)134217728);      // later Fb
    bf16*  VB   = (bf16*)(ws + (size_t)201326592);
    bf16*  wslot= (bf16*)(ws + (size_t)268435456);      // 2 MiB, reused per GEMM
    float* posb = (float*)(ws + (size_t)270532608);     // 512 KiB
    float* weff = (float*)(ws + (size_t)271056896);
    float* wcst = (float*)(ws + (size_t)271062016);
    bf16*  Xbf = buf0;
    bf16*  KB  = buf0;
    bf16*  Fb  = XS;

    const dim3 ggrid(CH/BN, MROWS/BM);   // (8, 256)

    prep_weff_kernel<<<dim3(KW), dim3(GCH), 0, stream>>>(W1, b1, w2, b2, weff, wcst);
    cvt_kernel<<<dim3(MROWS*CH/8/256), 256, 0, stream>>>(x, Xbf, MROWS*CH);

    cvt_kernel<<<dim3(CH*CH/8/256), 256, 0, stream>>>(Wq, wslot, CH*CH);
    gemm_mfma_kernel<false,bf16><<<ggrid, 256, 0, stream>>>(Xbf, wslot, bq, nullptr, Qb);

    offsets_kernel<<<dim3(SEQ/256, NBG), 256, 0, stream>>>(Qb, weff, wcst, posb);
    sample_kernel<<<dim3(SEQ, NBG), 256, 0, stream>>>(x, posb, XS);

    cvt_kernel<<<dim3(CH*CH/8/256), 256, 0, stream>>>(Wk, wslot, CH*CH);
    gemm_mfma_kernel<false,bf16><<<ggrid, 256, 0, stream>>>(XS, wslot, bk, nullptr, KB);

    cvt_kernel<<<dim3(CH*CH/8/256), 256, 0, stream>>>(Wv, wslot, CH*CH);
    gemm_mfma_kernel<true,bf16><<<ggrid, 256, 0, stream>>>(XS, wslot, bv, rpb, VB);

    attn_kernel<<<dim3(NBH), 256, 0, stream>>>(Qb, KB, VB, Fb);

    cvt_kernel<<<dim3(CH*CH/8/256), 256, 0, stream>>>(Wo, wslot, CH*CH);
    gemm_mfma_kernel<false,float><<<ggrid, 256, 0, stream>>>(Fb, wslot, bo, nullptr, (float*)d_out);
}

// Round 3
// 746.737 us; speedup vs baseline: 5.3778x; 1.5087x over previous
//
#include <hip/hip_runtime.h>
#include <hip/hip_bf16.h>
#include <stdint.h>

#define BATCH 16
#define SEQ   2048
#define CH    1024
#define NH    16
#define NG    4
#define KW    5
#define GCH   256
#define DHD   64
#define NBG   (BATCH*NG)   // 64
#define NBH   (BATCH*NH)   // 256
#define MROWS (BATCH*SEQ)  // 32768

#define BM 128
#define BN 128
#define BK 64

typedef __hip_bfloat16 bf16;
typedef float f32x4 __attribute__((ext_vector_type(4)));
typedef __bf16 bf16x8 __attribute__((ext_vector_type(8)));

// ---------------------------------------------------------------------------
// fp32 -> bf16 convert, 8 elems/thread
// ---------------------------------------------------------------------------
__global__ __launch_bounds__(256)
void cvt_kernel(const float* __restrict__ in, bf16* __restrict__ out, int n)
{
    int i = (blockIdx.x*256 + threadIdx.x)*8;
    if (i >= n) return;
    float4 f0 = *(const float4*)(in+i);
    float4 f1 = *(const float4*)(in+i+4);
    union { bf16 b[8]; uint4 u; } pk;
    pk.b[0]=__float2bfloat16(f0.x); pk.b[1]=__float2bfloat16(f0.y);
    pk.b[2]=__float2bfloat16(f0.z); pk.b[3]=__float2bfloat16(f0.w);
    pk.b[4]=__float2bfloat16(f1.x); pk.b[5]=__float2bfloat16(f1.y);
    pk.b[6]=__float2bfloat16(f1.z); pk.b[7]=__float2bfloat16(f1.w);
    *(uint4*)(out+i) = pk.u;
}

// ---------------------------------------------------------------------------
// Weff[kk][cj] = sum_co w2[co] * W1[co][cj][kk];  wcst = {b2, dot(w2,b1)}
// ---------------------------------------------------------------------------
__global__ void prep_weff_kernel(const float* __restrict__ W1, const float* __restrict__ b1,
                                 const float* __restrict__ w2, const float* __restrict__ b2,
                                 float* __restrict__ weff, float* __restrict__ wcst)
{
    int kk = blockIdx.x;          // 0..4
    int cj = threadIdx.x;         // 0..255
    float s = 0.f;
    for (int co=0; co<GCH; ++co)
        s += w2[co] * W1[((size_t)co*GCH + cj)*KW + kk];
    weff[kk*GCH + cj] = s;
    if (kk==0 && cj==0){
        float sb = 0.f;
        for (int co=0; co<GCH; ++co) sb += w2[co]*b1[co];
        wcst[0] = b2[0];
        wcst[1] = sb;
    }
}

// ---------------------------------------------------------------------------
// MFMA GEMM (m97 structure). MODE: 0 = bf16 [m][n], 1 = bf16 [m][n] + rpb,
// 2 = bf16 TRANSPOSED out [b][n][l] (LDS-staged tile transpose), 3 = f32 [m][n].
// ---------------------------------------------------------------------------
template<int MODE>
__global__ __launch_bounds__(256)
void gemm_mfma_kernel(const bf16* __restrict__ A, const bf16* __restrict__ Wb,
                      const float* __restrict__ bias, const float* __restrict__ rpb,
                      void* __restrict__ outp)
{
    __shared__ __align__(16) char smem[34816];
    __bf16* As = (__bf16*)smem;
    __bf16* Bs = As + BM*BK;
    const int t = threadIdx.x;
    const int w = t>>6, l = t&63;
    const int m0 = blockIdx.y*BM, n0 = blockIdx.x*BN;
    const int wr = w>>1, wc = w&1;
    const int lr = l&15;
    const int lk = (l>>4)*8;

    f32x4 acc[4][4];
    #pragma unroll
    for (int i=0;i<4;++i)
        #pragma unroll
        for (int j=0;j<4;++j) acc[i][j] = (f32x4){0.f,0.f,0.f,0.f};

    const int srow = w*8 + (l>>3);
    const int scol = (l&7)*8;
    const bf16* Ag = A  + (size_t)m0*CH;
    const bf16* Bg = Wb + (size_t)n0*CH;

    for (int kt=0; kt<CH; kt+=BK){
        #pragma unroll
        for (int it=0; it<4; ++it){
            int row = it*32 + srow;
            __builtin_amdgcn_global_load_lds(
                (const __attribute__((address_space(1))) void*)(Ag + (size_t)row*CH + kt + scol),
                (__attribute__((address_space(3))) void*)(As + (it*32 + w*8)*BK),
                16, 0, 0);
            __builtin_amdgcn_global_load_lds(
                (const __attribute__((address_space(1))) void*)(Bg + (size_t)row*CH + kt + scol),
                (__attribute__((address_space(3))) void*)(Bs + (it*32 + w*8)*BK),
                16, 0, 0);
        }
        __syncthreads();
        #pragma unroll
        for (int ks=0; ks<2; ++ks){
            bf16x8 af[4], bw[4];
            #pragma unroll
            for (int i=0;i<4;++i){
                af[i] = *(const bf16x8*)(As + (wr*64 + i*16 + lr)*BK + ks*32 + lk);
                bw[i] = *(const bf16x8*)(Bs + (wc*64 + i*16 + lr)*BK + ks*32 + lk);
            }
            #pragma unroll
            for (int i=0;i<4;++i)
                #pragma unroll
                for (int j=0;j<4;++j)
                    acc[i][j] = __builtin_amdgcn_mfma_f32_16x16x32_bf16(af[i], bw[j], acc[i][j], 0,0,0);
        }
        __syncthreads();
    }

    float bs[4];
    #pragma unroll
    for (int j=0;j<4;++j) bs[j] = bias[n0 + wc*64 + j*16 + lr];

    if constexpr (MODE == 2){
        // stage tile in LDS as T[n_local][l_local], LD=136 (16B-aligned rows)
        __bf16* T = (__bf16*)smem;
        #pragma unroll
        for (int i=0;i<4;++i)
            #pragma unroll
            for (int j=0;j<4;++j)
                #pragma unroll
                for (int r=0;r<4;++r)
                    T[(wc*64 + j*16 + lr)*136 + wr*64 + i*16 + (l>>4)*4 + r] =
                        (__bf16)__float2bfloat16(acc[i][j][r] + bs[j]);
        __syncthreads();
        const int row = t >> 1, half = t & 1;
        const int bb = m0 >> 11, l0g = m0 & (SEQ-1);
        bf16* dst = (bf16*)outp + ((size_t)(bb*CH + n0 + row))*SEQ + l0g + half*64;
        const __bf16* srcT = T + row*136 + half*64;
        #pragma unroll
        for (int k2=0;k2<8;++k2)
            *(uint4*)(dst + k2*8) = *(const uint4*)(srcT + k2*8);
    } else {
        #pragma unroll
        for (int i=0;i<4;++i){
            #pragma unroll
            for (int r=0;r<4;++r){
                int mg = m0 + wr*64 + i*16 + (l>>4)*4 + r;
                int lseq = mg & (SEQ-1);
                #pragma unroll
                for (int j=0;j<4;++j){
                    int ng = n0 + wc*64 + j*16 + lr;
                    float v = acc[i][j][r] + bs[j];
                    if constexpr (MODE == 1) v += rpb[(size_t)ng*SEQ + lseq];
                    if constexpr (MODE == 3)
                        ((float*)outp)[(size_t)mg*CH + ng] = v;
                    else
                        ((bf16*)outp)[(size_t)mg*CH + ng] = __float2bfloat16(v);
                }
            }
        }
    }
}

// ---------------------------------------------------------------------------
// offset network from QT[b][ch][l]: P5 rows + tanh + sampling position
// ---------------------------------------------------------------------------
__global__ __launch_bounds__(256)
void offsets_kernel(const bf16* __restrict__ QT, const float* __restrict__ weff,
                    const float* __restrict__ wcst, float* __restrict__ posb)
{
    __shared__ float P5L[264][5];
    __shared__ float weffL[KW][GCH];
    const int t = threadIdx.x;
    const int chunk = blockIdx.x, bg = blockIdx.y;
    const int b = bg>>2, g = bg&3;
    const int l0 = chunk*256;

    for (int i = t; i < KW*GCH; i += 256) weffL[i/GCH][i&(GCH-1)] = weff[i];
    __syncthreads();

    for (int idx = t; idx < 260; idx += 256){
        int j = l0 - 4 + idx;
        float a0=0.f,a1=0.f,a2=0.f,a3=0.f,a4=0.f;
        if (j >= 0 && j < SEQ){
            const bf16* src = QT + ((size_t)(b*CH + g*GCH))*SEQ + j;
            #pragma unroll 4
            for (int ch=0; ch<GCH; ++ch){
                float v = __bfloat162float(src[(size_t)ch*SEQ]);
                a0 += v*weffL[0][ch]; a1 += v*weffL[1][ch]; a2 += v*weffL[2][ch];
                a3 += v*weffL[3][ch]; a4 += v*weffL[4][ch];
            }
        }
        P5L[idx][0]=a0; P5L[idx][1]=a1; P5L[idx][2]=a2; P5L[idx][3]=a3; P5L[idx][4]=a4;
    }
    __syncthreads();

    int lp = l0 + t;
    float b2 = wcst[0], wb1 = wcst[1];
    float o;
    if (lp < 2){
        o = b2;
    } else {
        float s = b2 + wb1;
        #pragma unroll
        for (int kk=0;kk<KW;++kk){
            int j = lp - 4 + kk;
            if (j >= 0 && j < SEQ) s += P5L[t+kk][kk];
        }
        o = s;
    }
    float off = tanhf(o) * (float)KW;
    posb[bg*SEQ + lp] = ((float)lp + off) * (2048.0f/2051.0f) - 0.5f;
}

// ---------------------------------------------------------------------------
// bilinear zero-pad sampler from bf16 x: XS[b][l'][g*256+ci]
// ---------------------------------------------------------------------------
__global__ __launch_bounds__(256)
void sample_kernel(const bf16* __restrict__ Xbf, const float* __restrict__ posb,
                   bf16* __restrict__ XS)
{
    const int ci = threadIdx.x, bg = blockIdx.y;
    const int b = bg>>2, g = bg&3;
    const int lp0 = blockIdx.x*8;
    #pragma unroll
    for (int s8=0; s8<8; ++s8){
        int lp = lp0 + s8;
        float p  = posb[bg*SEQ + lp];
        float fl = floorf(p);
        float w1 = p - fl;
        int i0 = (int)fl;
        float v = 0.f;
        if (i0 >= 0 && i0 < SEQ)
            v += __bfloat162float(Xbf[((size_t)(b*SEQ + i0))*CH + g*GCH + ci]) * (1.f - w1);
        if (i0+1 >= 0 && i0+1 < SEQ)
            v += __bfloat162float(Xbf[((size_t)(b*SEQ + i0 + 1))*CH + g*GCH + ci]) * w1;
        XS[((size_t)(b*SEQ + lp))*CH + g*GCH + ci] = __float2bfloat16(v);
    }
}

// ---------------------------------------------------------------------------
// S = Q K^T (per head, MFMA over L with 512/wave K-split) + softmax -> P bf16
// ---------------------------------------------------------------------------
__global__ __launch_bounds__(256)
void attn_s_kernel(const bf16* __restrict__ QT, const bf16* __restrict__ KT,
                   bf16* __restrict__ Pbuf)
{
    __shared__ float Sc[64][69];
    __shared__ float red[64][4];
    __shared__ float mrow[64];
    __shared__ float sinv[64];
    const int t = threadIdx.x, w = t>>6, l = t&63;
    const int bh = blockIdx.x, b = bh>>4, h = bh&15;
    const bf16* q = QT + ((size_t)(b*CH + h*DHD))*SEQ;
    const bf16* k = KT + ((size_t)(b*CH + h*DHD))*SEQ;
    const int lr = l&15, lk = (l>>4)*8;

    f32x4 acc[4][4];
    #pragma unroll
    for (int i=0;i<4;++i)
        #pragma unroll
        for (int j=0;j<4;++j) acc[i][j] = (f32x4){0.f,0.f,0.f,0.f};

    for (int ks=0; ks<16; ++ks){
        int kp = w*512 + ks*32 + lk;
        bf16x8 af[4], bk8[4];
        #pragma unroll
        for (int i=0;i<4;++i) af[i]  = *(const bf16x8*)(q + (size_t)(i*16+lr)*SEQ + kp);
        #pragma unroll
        for (int j=0;j<4;++j) bk8[j] = *(const bf16x8*)(k + (size_t)(j*16+lr)*SEQ + kp);
        #pragma unroll
        for (int i=0;i<4;++i)
            #pragma unroll
            for (int j=0;j<4;++j)
                acc[i][j] = __builtin_amdgcn_mfma_f32_16x16x32_bf16(af[i], bk8[j], acc[i][j], 0,0,0);
    }
    // cross-wave reduce into Sc
    for (int wv=0; wv<4; ++wv){
        if (w == wv){
            #pragma unroll
            for (int i=0;i<4;++i)
                #pragma unroll
                for (int j=0;j<4;++j)
                    #pragma unroll
                    for (int r=0;r<4;++r){
                        int m = i*16 + (l>>4)*4 + r, n = j*16 + lr;
                        if (wv==0) Sc[m][n]  = acc[i][j][r];
                        else       Sc[m][n] += acc[i][j][r];
                    }
        }
        __syncthreads();
    }
    // softmax (scale 1/32), 4 threads per row
    const int r0 = t & 63, p = t >> 6;
    const float SCALE = 0.03125f;
    float mx = -1e30f;
    #pragma unroll
    for (int c=0;c<16;++c) mx = fmaxf(mx, Sc[r0][p*16+c]*SCALE);
    red[r0][p] = mx;
    __syncthreads();
    if (t < 64) mrow[t] = fmaxf(fmaxf(red[t][0],red[t][1]), fmaxf(red[t][2],red[t][3]));
    __syncthreads();
    float m = mrow[r0], s = 0.f;
    #pragma unroll
    for (int c=0;c<16;++c){
        float e = expf(Sc[r0][p*16+c]*SCALE - m);
        Sc[r0][p*16+c] = e;
        s += e;
    }
    red[r0][p] = s;
    __syncthreads();
    if (t < 64) sinv[t] = 1.f/(red[t][0]+red[t][1]+red[t][2]+red[t][3]);
    __syncthreads();
    float inv = sinv[r0];
    union { bf16 b[8]; uint4 u; } p0, p1;
    #pragma unroll
    for (int e=0;e<8;++e){
        p0.b[e] = __float2bfloat16(Sc[r0][p*16+e]*inv);
        p1.b[e] = __float2bfloat16(Sc[r0][p*16+8+e]*inv);
    }
    bf16* dst = Pbuf + (size_t)bh*4096 + r0*64 + p*16;
    *(uint4*)dst       = p0.u;
    *(uint4*)(dst + 8) = p1.u;
}

// ---------------------------------------------------------------------------
// F[b][l][h*64+i] = sum_j P[i][j] V[b][l][h*64+j]  (MFMA, V natural layout)
// ---------------------------------------------------------------------------
__global__ __launch_bounds__(256)
void attn_pv_kernel(const bf16* __restrict__ Pbuf, const bf16* __restrict__ V,
                    bf16* __restrict__ F)
{
    __shared__ __bf16 Pl[64][72];
    const int t = threadIdx.x, w = t>>6, l = t&63;
    const int chunk = blockIdx.x, bh = blockIdx.y;
    const int b = bh>>4, h = bh&15;
    {
        int row = t>>2, coff = (t&3)*16;
        const bf16* src = Pbuf + (size_t)bh*4096 + row*64 + coff;
        *(uint4*)&Pl[row][coff]   = *(const uint4*)src;
        *(uint4*)&Pl[row][coff+8] = *(const uint4*)(src+8);
    }
    __syncthreads();
    const int lr = l&15, lk = (l>>4)*8;
    const int lw = chunk*256 + w*64;

    f32x4 acc[4][4];
    #pragma unroll
    for (int i=0;i<4;++i)
        #pragma unroll
        for (int j=0;j<4;++j) acc[i][j] = (f32x4){0.f,0.f,0.f,0.f};

    #pragma unroll
    for (int ks=0; ks<2; ++ks){
        bf16x8 pf[4], vf[4];
        #pragma unroll
        for (int ni=0;ni<4;++ni) pf[ni] = *(const bf16x8*)&Pl[ni*16+lr][ks*32+lk];
        #pragma unroll
        for (int mi=0;mi<4;++mi)
            vf[mi] = *(const bf16x8*)(V + ((size_t)(b*SEQ + lw + mi*16 + lr))*CH + h*DHD + ks*32 + lk);
        #pragma unroll
        for (int mi=0;mi<4;++mi)
            #pragma unroll
            for (int ni=0;ni<4;++ni)
                acc[mi][ni] = __builtin_amdgcn_mfma_f32_16x16x32_bf16(vf[mi], pf[ni], acc[mi][ni], 0,0,0);
    }
    #pragma unroll
    for (int mi=0;mi<4;++mi){
        #pragma unroll
        for (int r=0;r<4;++r){
            int lpos = lw + mi*16 + (l>>4)*4 + r;
            #pragma unroll
            for (int ni=0;ni<4;++ni)
                F[((size_t)(b*SEQ + lpos))*CH + h*DHD + ni*16 + lr] =
                    __float2bfloat16(acc[mi][ni][r]);
        }
    }
}

// ---------------------------------------------------------------------------
extern "C" void kernel_launch(void* const* d_in, const int* in_sizes, int n_in,
                              void* d_out, int out_size, void* d_ws, size_t ws_size,
                              hipStream_t stream)
{
    const float* x   = (const float*)d_in[0];
    const float* Wq  = (const float*)d_in[1];
    const float* bq  = (const float*)d_in[2];
    const float* Wk  = (const float*)d_in[3];
    const float* bk  = (const float*)d_in[4];
    const float* Wv  = (const float*)d_in[5];
    const float* bv  = (const float*)d_in[6];
    const float* W1  = (const float*)d_in[7];
    const float* b1  = (const float*)d_in[8];
    const float* w2  = (const float*)d_in[9];
    const float* b2  = (const float*)d_in[10];
    const float* rpb = (const float*)d_in[11];
    const float* Wo  = (const float*)d_in[12];
    const float* bo  = (const float*)d_in[13];

    char* ws = (char*)d_ws;
    bf16*  Xbf  = (bf16*)(ws);                          // 64 MiB; later KT
    bf16*  QT   = (bf16*)(ws + (size_t) 67108864);      // 64 MiB [b][ch][l]
    bf16*  XS   = (bf16*)(ws + (size_t)134217728);      // 64 MiB; later F
    bf16*  VB   = (bf16*)(ws + (size_t)201326592);      // 64 MiB
    bf16*  Pbuf = (bf16*)(ws + (size_t)268435456);      // 2 MiB
    bf16*  wslot= (bf16*)(ws + (size_t)270532608);      // 2 MiB
    float* posb = (float*)(ws + (size_t)272629760);     // 512 KiB
    float* weff = (float*)(ws + (size_t)273154048);
    float* wcst = (float*)(ws + (size_t)273159168);
    bf16*  KT = Xbf;     // Xbf dead after sample_kernel
    bf16*  Fb = XS;      // XS dead after K/V GEMMs

    const dim3 ggrid(CH/BN, MROWS/BM);   // (8, 256)

    prep_weff_kernel<<<dim3(KW), dim3(GCH), 0, stream>>>(W1, b1, w2, b2, weff, wcst);
    cvt_kernel<<<dim3(MROWS*CH/8/256), 256, 0, stream>>>(x, Xbf, MROWS*CH);

    cvt_kernel<<<dim3(CH*CH/8/256), 256, 0, stream>>>(Wq, wslot, CH*CH);
    gemm_mfma_kernel<2><<<ggrid, 256, 0, stream>>>(Xbf, wslot, bq, nullptr, QT);

    offsets_kernel<<<dim3(SEQ/256, NBG), 256, 0, stream>>>(QT, weff, wcst, posb);
    sample_kernel<<<dim3(SEQ/8, NBG), 256, 0, stream>>>(Xbf, posb, XS);

    cvt_kernel<<<dim3(CH*CH/8/256), 256, 0, stream>>>(Wk, wslot, CH*CH);
    gemm_mfma_kernel<2><<<ggrid, 256, 0, stream>>>(XS, wslot, bk, nullptr, KT);

    cvt_kernel<<<dim3(CH*CH/8/256), 256, 0, stream>>>(Wv, wslot, CH*CH);
    gemm_mfma_kernel<1><<<ggrid, 256, 0, stream>>>(XS, wslot, bv, rpb, VB);

    attn_s_kernel<<<dim3(NBH), 256, 0, stream>>>(QT, KT, Pbuf);
    attn_pv_kernel<<<dim3(8, NBH), 256, 0, stream>>>(Pbuf, VB, Fb);

    cvt_kernel<<<dim3(CH*CH/8/256), 256, 0, stream>>>(Wo, wslot, CH*CH);
    gemm_mfma_kernel<3><<<ggrid, 256, 0, stream>>>(Fb, wslot, bo, nullptr, (float*)d_out);
}

// Round 5
// 647.063 us; speedup vs baseline: 6.2062x; 1.1540x over previous
//
#include <hip/hip_runtime.h>
#include <hip/hip_bf16.h>
#include <stdint.h>

#define BATCH 16
#define SEQ   2048
#define CH    1024
#define NH    16
#define NG    4
#define KW    5
#define GCH   256
#define DHD   64
#define NBG   (BATCH*NG)   // 64
#define NBH   (BATCH*NH)   // 256
#define MROWS (BATCH*SEQ)  // 32768

typedef __hip_bfloat16 bf16;
typedef float f32x4 __attribute__((ext_vector_type(4)));
typedef __bf16 bf16x8 __attribute__((ext_vector_type(8)));

// ---------------------------------------------------------------------------
// fp32 -> bf16 convert, 8 elems/thread
// ---------------------------------------------------------------------------
__global__ __launch_bounds__(256)
void cvt_kernel(const float* __restrict__ in, bf16* __restrict__ out, int n)
{
    int i = (blockIdx.x*256 + threadIdx.x)*8;
    if (i >= n) return;
    float4 f0 = *(const float4*)(in+i);
    float4 f1 = *(const float4*)(in+i+4);
    union { bf16 b[8]; uint4 u; } pk;
    pk.b[0]=__float2bfloat16(f0.x); pk.b[1]=__float2bfloat16(f0.y);
    pk.b[2]=__float2bfloat16(f0.z); pk.b[3]=__float2bfloat16(f0.w);
    pk.b[4]=__float2bfloat16(f1.x); pk.b[5]=__float2bfloat16(f1.y);
    pk.b[6]=__float2bfloat16(f1.z); pk.b[7]=__float2bfloat16(f1.w);
    *(uint4*)(out+i) = pk.u;
}

// ---------------------------------------------------------------------------
// Weff[kk][cj] = sum_co w2[co] * W1[co][cj][kk];  wcst = {b2, dot(w2,b1)}
// ---------------------------------------------------------------------------
__global__ void prep_weff_kernel(const float* __restrict__ W1, const float* __restrict__ b1,
                                 const float* __restrict__ w2, const float* __restrict__ b2,
                                 float* __restrict__ weff, float* __restrict__ wcst)
{
    int kk = blockIdx.x;          // 0..4
    int cj = threadIdx.x;         // 0..255
    float s = 0.f;
    for (int co=0; co<GCH; ++co)
        s += w2[co] * W1[((size_t)co*GCH + cj)*KW + kk];
    weff[kk*GCH + cj] = s;
    if (kk==0 && cj==0){
        float sb = 0.f;
        for (int co=0; co<GCH; ++co) sb += w2[co]*b1[co];
        wcst[0] = b2[0];
        wcst[1] = sb;
    }
}

// ---------------------------------------------------------------------------
// 256x256-tile pipelined MFMA GEMM. C[m][n] = sum_k A[m][k]*W[n][k] + bias
// MODE: 0 = bf16 [m][n], 1 = bf16 [m][n]+rpb, 2 = bf16 transposed [b][n][l],
// 3 = f32 [m][n].
// BK=32, 3 LDS buffers (96 KiB) rotating. Race-free 2-barrier schedule:
//   vmcnt(8)   -> my STAGE(t) loads landed
//   barrier    -> ALL waves' STAGE(t) landed        (publish writes)
//   ds_read buf[t%3]
//   lgkmcnt(0) -> my reads in registers
//   barrier    -> ALL waves' reads of buf[t%3] done (publish reads)
//   STAGE(t+3 -> buf[t%3])  (overwrite just-consumed buffer)
//   MFMA x32 (setprio-wrapped)
// Counted vmcnt never drains to 0 mid-loop (T3/T4). T2 XOR-swizzle via
// pre-swizzled global source + swizzled ds_read (involution on disjoint
// bits). T1: 4 column-blocks of each A-panel grouped per XCD.
// ---------------------------------------------------------------------------
template<int MODE>
__global__ __launch_bounds__(512, 2)
void gemm256_kernel(const bf16* __restrict__ A, const bf16* __restrict__ Wb,
                    const float* __restrict__ bias, const float* __restrict__ rpb,
                    void* __restrict__ outp)
{
    __shared__ __bf16 SM[3*16384];   // 3 x (A 8192 + B 8192 elems) = 96 KiB
    const int t = threadIdx.x;
    const int w = t>>6, l = t&63;
    const int wrow = w>>2, wcol = w&3;     // 2 x 4 waves, 128x64 out each
    const int lr = l&15, kslot = l>>4;

    // block map: panel-mates (same A rows, 4 n-blocks) on same XCD
    const int lin = blockIdx.x;            // 0..511
    const int xcd = lin&7, sblk = lin>>3;  // sblk: 0..63
    const int m0 = (xcd*16 + (sblk>>2))*256;
    const int n0 = (sblk&3)*256;

    const bf16* Ag = A  + (size_t)m0*CH;
    const bf16* Bg = Wb + (size_t)n0*CH;

    // staging source: linear LDS byte o <- global element at swz(o)
    // swz(o) = o ^ (((o>>7)&3)<<4)  (row bits 1-2 -> 16B-slot bits; involution)
    int srow[2], scol[2];
    #pragma unroll
    for (int r=0;r<2;++r){
        int o = (t + 512*r)*16;
        int e = o ^ (((o>>7)&3)<<4);
        srow[r] = e>>6;            // 64B rows (32 bf16)
        scol[r] = (e&63)>>1;
    }

    auto STAGE = [&](int tile, int buf){
        const int kt = tile*32;
        __bf16* ab = SM + buf*16384;
        __bf16* bb = ab + 8192;
        #pragma unroll
        for (int r=0;r<2;++r){
            __builtin_amdgcn_global_load_lds(
                (const __attribute__((address_space(1))) void*)(Ag + (size_t)srow[r]*CH + kt + scol[r]),
                (__attribute__((address_space(3))) void*)(ab + w*512 + r*4096), 16, 0, 0);
            __builtin_amdgcn_global_load_lds(
                (const __attribute__((address_space(1))) void*)(Bg + (size_t)srow[r]*CH + kt + scol[r]),
                (__attribute__((address_space(3))) void*)(bb + w*512 + r*4096), 16, 0, 0);
        }
    };

    f32x4 acc[8][4];
    #pragma unroll
    for (int i=0;i<8;++i)
        #pragma unroll
        for (int j=0;j<4;++j) acc[i][j] = (f32x4){0.f,0.f,0.f,0.f};

    STAGE(0, 0);
    STAGE(1, 1);
    STAGE(2, 2);

    const int NT = CH/32;   // 32
    for (int tt=0; tt<NT; ++tt){
        const int cur = tt%3;
        const int rem = NT-1 - tt;          // tiles prefetched beyond tt
        // drain my STAGE(tt) loads; leave later tiles' loads in flight
        if (rem >= 2)      asm volatile("s_waitcnt vmcnt(8)" ::: "memory");
        else if (rem == 1) asm volatile("s_waitcnt vmcnt(4)" ::: "memory");
        else               asm volatile("s_waitcnt vmcnt(0)" ::: "memory");
        __builtin_amdgcn_s_barrier();       // ALL waves' STAGE(tt) landed

        const __bf16* As_ = SM + cur*16384;
        const __bf16* Bs_ = As_ + 8192;
        bf16x8 af[8], bfr[4];
        #pragma unroll
        for (int fi=0; fi<8; ++fi){
            int row = wrow*128 + fi*16 + lr;
            int o = row*64 + kslot*16;
            o ^= ((o>>7)&3)<<4;
            af[fi] = *(const bf16x8*)(As_ + (o>>1));
        }
        #pragma unroll
        for (int fj=0; fj<4; ++fj){
            int row = wcol*64 + fj*16 + lr;
            int o = row*64 + kslot*16;
            o ^= ((o>>7)&3)<<4;
            bfr[fj] = *(const bf16x8*)(Bs_ + (o>>1));
        }
        asm volatile("s_waitcnt lgkmcnt(0)" ::: "memory");  // my reads in regs
        __builtin_amdgcn_s_barrier();       // ALL waves done reading buf[cur]

        if (tt+3 < NT) STAGE(tt+3, cur);    // overwrite just-consumed buffer

        __builtin_amdgcn_s_setprio(1);
        #pragma unroll
        for (int fi=0; fi<8; ++fi)
            #pragma unroll
            for (int fj=0; fj<4; ++fj)
                acc[fi][fj] = __builtin_amdgcn_mfma_f32_16x16x32_bf16(af[fi], bfr[fj], acc[fi][fj], 0,0,0);
        __builtin_amdgcn_s_setprio(0);
    }

    float bs[4];
    #pragma unroll
    for (int fj=0;fj<4;++fj) bs[fj] = bias[n0 + wcol*64 + fj*16 + lr];

    if constexpr (MODE == 2){
        const int bb2 = m0 >> 11;
        const int l0g = m0 & (SEQ-1);
        bf16* outT = (bf16*)outp;
        #pragma unroll
        for (int fi=0; fi<8; ++fi){
            int rowl = wrow*128 + fi*16 + kslot*4;
            #pragma unroll
            for (int fj=0; fj<4; ++fj){
                int col = n0 + wcol*64 + fj*16 + lr;
                union { bf16 h[4]; uint2 u; } pk;
                #pragma unroll
                for (int r=0;r<4;++r) pk.h[r] = __float2bfloat16(acc[fi][fj][r] + bs[fj]);
                *(uint2*)(outT + ((size_t)(bb2*CH + col))*SEQ + l0g + rowl) = pk.u;
            }
        }
    } else {
        #pragma unroll
        for (int fi=0; fi<8; ++fi){
            #pragma unroll
            for (int r=0;r<4;++r){
                int mg = m0 + wrow*128 + fi*16 + kslot*4 + r;
                int lseq = mg & (SEQ-1);
                #pragma unroll
                for (int fj=0; fj<4; ++fj){
                    int ng = n0 + wcol*64 + fj*16 + lr;
                    float v = acc[fi][fj][r] + bs[fj];
                    if constexpr (MODE==1) v += rpb[(size_t)ng*SEQ + lseq];
                    if constexpr (MODE==3)
                        ((float*)outp)[(size_t)mg*CH + ng] = v;
                    else
                        ((bf16*)outp)[(size_t)mg*CH + ng] = __float2bfloat16(v);
                }
            }
        }
    }
}

// ---------------------------------------------------------------------------
// offset network from QT[b][ch][l]: P5 rows + tanh + sampling position
// ---------------------------------------------------------------------------
__global__ __launch_bounds__(256)
void offsets_kernel(const bf16* __restrict__ QT, const float* __restrict__ weff,
                    const float* __restrict__ wcst, float* __restrict__ posb)
{
    __shared__ float P5L[264][5];
    __shared__ float weffL[KW][GCH];
    const int t = threadIdx.x;
    const int chunk = blockIdx.x, bg = blockIdx.y;
    const int b = bg>>2, g = bg&3;
    const int l0 = chunk*256;

    for (int i = t; i < KW*GCH; i += 256) weffL[i/GCH][i&(GCH-1)] = weff[i];
    __syncthreads();

    for (int idx = t; idx < 260; idx += 256){
        int j = l0 - 4 + idx;
        float a0=0.f,a1=0.f,a2=0.f,a3=0.f,a4=0.f;
        if (j >= 0 && j < SEQ){
            const bf16* src = QT + ((size_t)(b*CH + g*GCH))*SEQ + j;
            #pragma unroll 4
            for (int ch=0; ch<GCH; ++ch){
                float v = __bfloat162float(src[(size_t)ch*SEQ]);
                a0 += v*weffL[0][ch]; a1 += v*weffL[1][ch]; a2 += v*weffL[2][ch];
                a3 += v*weffL[3][ch]; a4 += v*weffL[4][ch];
            }
        }
        P5L[idx][0]=a0; P5L[idx][1]=a1; P5L[idx][2]=a2; P5L[idx][3]=a3; P5L[idx][4]=a4;
    }
    __syncthreads();

    int lp = l0 + t;
    float b2 = wcst[0], wb1 = wcst[1];
    float o;
    if (lp < 2){
        o = b2;
    } else {
        float s = b2 + wb1;
        #pragma unroll
        for (int kk=0;kk<KW;++kk){
            int j = lp - 4 + kk;
            if (j >= 0 && j < SEQ) s += P5L[t+kk][kk];
        }
        o = s;
    }
    float off = tanhf(o) * (float)KW;
    posb[bg*SEQ + lp] = ((float)lp + off) * (2048.0f/2051.0f) - 0.5f;
}

// ---------------------------------------------------------------------------
// bilinear zero-pad sampler from bf16 x: XS[b][l'][g*256+ci]
// ---------------------------------------------------------------------------
__global__ __launch_bounds__(256)
void sample_kernel(const bf16* __restrict__ Xbf, const float* __restrict__ posb,
                   bf16* __restrict__ XS)
{
    const int ci = threadIdx.x, bg = blockIdx.y;
    const int b = bg>>2, g = bg&3;
    const int lp0 = blockIdx.x*8;
    #pragma unroll
    for (int s8=0; s8<8; ++s8){
        int lp = lp0 + s8;
        float p  = posb[bg*SEQ + lp];
        float fl = floorf(p);
        float w1 = p - fl;
        int i0 = (int)fl;
        float v = 0.f;
        if (i0 >= 0 && i0 < SEQ)
            v += __bfloat162float(Xbf[((size_t)(b*SEQ + i0))*CH + g*GCH + ci]) * (1.f - w1);
        if (i0+1 >= 0 && i0+1 < SEQ)
            v += __bfloat162float(Xbf[((size_t)(b*SEQ + i0 + 1))*CH + g*GCH + ci]) * w1;
        XS[((size_t)(b*SEQ + lp))*CH + g*GCH + ci] = __float2bfloat16(v);
    }
}

// ---------------------------------------------------------------------------
// S = Q K^T (per head, MFMA over L with 512/wave K-split) + softmax -> P bf16
// ---------------------------------------------------------------------------
__global__ __launch_bounds__(256)
void attn_s_kernel(const bf16* __restrict__ QT, const bf16* __restrict__ KT,
                   bf16* __restrict__ Pbuf)
{
    __shared__ float Sc[64][69];
    __shared__ float red[64][4];
    __shared__ float mrow[64];
    __shared__ float sinv[64];
    const int t = threadIdx.x, w = t>>6, l = t&63;
    const int bh = blockIdx.x, b = bh>>4, h = bh&15;
    const bf16* q = QT + ((size_t)(b*CH + h*DHD))*SEQ;
    const bf16* k = KT + ((size_t)(b*CH + h*DHD))*SEQ;
    const int lr = l&15, lk = (l>>4)*8;

    f32x4 acc[4][4];
    #pragma unroll
    for (int i=0;i<4;++i)
        #pragma unroll
        for (int j=0;j<4;++j) acc[i][j] = (f32x4){0.f,0.f,0.f,0.f};

    for (int ks=0; ks<16; ++ks){
        int kp = w*512 + ks*32 + lk;
        bf16x8 af[4], bk8[4];
        #pragma unroll
        for (int i=0;i<4;++i) af[i]  = *(const bf16x8*)(q + (size_t)(i*16+lr)*SEQ + kp);
        #pragma unroll
        for (int j=0;j<4;++j) bk8[j] = *(const bf16x8*)(k + (size_t)(j*16+lr)*SEQ + kp);
        #pragma unroll
        for (int i=0;i<4;++i)
            #pragma unroll
            for (int j=0;j<4;++j)
                acc[i][j] = __builtin_amdgcn_mfma_f32_16x16x32_bf16(af[i], bk8[j], acc[i][j], 0,0,0);
    }
    // cross-wave reduce into Sc
    for (int wv=0; wv<4; ++wv){
        if (w == wv){
            #pragma unroll
            for (int i=0;i<4;++i)
                #pragma unroll
                for (int j=0;j<4;++j)
                    #pragma unroll
                    for (int r=0;r<4;++r){
                        int m = i*16 + (l>>4)*4 + r, n = j*16 + lr;
                        if (wv==0) Sc[m][n]  = acc[i][j][r];
                        else       Sc[m][n] += acc[i][j][r];
                    }
        }
        __syncthreads();
    }
    // softmax (scale 1/32), 4 threads per row
    const int r0 = t & 63, p = t >> 6;
    const float SCALE = 0.03125f;
    float mx = -1e30f;
    #pragma unroll
    for (int c=0;c<16;++c) mx = fmaxf(mx, Sc[r0][p*16+c]*SCALE);
    red[r0][p] = mx;
    __syncthreads();
    if (t < 64) mrow[t] = fmaxf(fmaxf(red[t][0],red[t][1]), fmaxf(red[t][2],red[t][3]));
    __syncthreads();
    float m = mrow[r0], s = 0.f;
    #pragma unroll
    for (int c=0;c<16;++c){
        float e = expf(Sc[r0][p*16+c]*SCALE - m);
        Sc[r0][p*16+c] = e;
        s += e;
    }
    red[r0][p] = s;
    __syncthreads();
    if (t < 64) sinv[t] = 1.f/(red[t][0]+red[t][1]+red[t][2]+red[t][3]);
    __syncthreads();
    float inv = sinv[r0];
    union { bf16 b[8]; uint4 u; } p0, p1;
    #pragma unroll
    for (int e=0;e<8;++e){
        p0.b[e] = __float2bfloat16(Sc[r0][p*16+e]*inv);
        p1.b[e] = __float2bfloat16(Sc[r0][p*16+8+e]*inv);
    }
    bf16* dst = Pbuf + (size_t)bh*4096 + r0*64 + p*16;
    *(uint4*)dst       = p0.u;
    *(uint4*)(dst + 8) = p1.u;
}

// ---------------------------------------------------------------------------
// F[b][l][h*64+i] = sum_j P[i][j] V[b][l][h*64+j]  (MFMA, V natural layout)
// ---------------------------------------------------------------------------
__global__ __launch_bounds__(256)
void attn_pv_kernel(const bf16* __restrict__ Pbuf, const bf16* __restrict__ V,
                    bf16* __restrict__ F)
{
    __shared__ __bf16 Pl[64][72];
    const int t = threadIdx.x, w = t>>6, l = t&63;
    const int chunk = blockIdx.x, bh = blockIdx.y;
    const int b = bh>>4, h = bh&15;
    {
        int row = t>>2, coff = (t&3)*16;
        const bf16* src = Pbuf + (size_t)bh*4096 + row*64 + coff;
        *(uint4*)&Pl[row][coff]   = *(const uint4*)src;
        *(uint4*)&Pl[row][coff+8] = *(const uint4*)(src+8);
    }
    __syncthreads();
    const int lr = l&15, lk = (l>>4)*8;
    const int lw = chunk*256 + w*64;

    f32x4 acc[4][4];
    #pragma unroll
    for (int i=0;i<4;++i)
        #pragma unroll
        for (int j=0;j<4;++j) acc[i][j] = (f32x4){0.f,0.f,0.f,0.f};

    #pragma unroll
    for (int ks=0; ks<2; ++ks){
        bf16x8 pf[4], vf[4];
        #pragma unroll
        for (int ni=0;ni<4;++ni) pf[ni] = *(const bf16x8*)&Pl[ni*16+lr][ks*32+lk];
        #pragma unroll
        for (int mi=0;mi<4;++mi)
            vf[mi] = *(const bf16x8*)(V + ((size_t)(b*SEQ + lw + mi*16 + lr))*CH + h*DHD + ks*32 + lk);
        #pragma unroll
        for (int mi=0;mi<4;++mi)
            #pragma unroll
            for (int ni=0;ni<4;++ni)
                acc[mi][ni] = __builtin_amdgcn_mfma_f32_16x16x32_bf16(vf[mi], pf[ni], acc[mi][ni], 0,0,0);
    }
    #pragma unroll
    for (int mi=0;mi<4;++mi){
        #pragma unroll
        for (int r=0;r<4;++r){
            int lpos = lw + mi*16 + (l>>4)*4 + r;
            #pragma unroll
            for (int ni=0;ni<4;++ni)
                F[((size_t)(b*SEQ + lpos))*CH + h*DHD + ni*16 + lr] =
                    __float2bfloat16(acc[mi][ni][r]);
        }
    }
}

// ---------------------------------------------------------------------------
extern "C" void kernel_launch(void* const* d_in, const int* in_sizes, int n_in,
                              void* d_out, int out_size, void* d_ws, size_t ws_size,
                              hipStream_t stream)
{
    const float* x   = (const float*)d_in[0];
    const float* Wq  = (const float*)d_in[1];
    const float* bq  = (const float*)d_in[2];
    const float* Wk  = (const float*)d_in[3];
    const float* bk  = (const float*)d_in[4];
    const float* Wv  = (const float*)d_in[5];
    const float* bv  = (const float*)d_in[6];
    const float* W1  = (const float*)d_in[7];
    const float* b1  = (const float*)d_in[8];
    const float* w2  = (const float*)d_in[9];
    const float* b2  = (const float*)d_in[10];
    const float* rpb = (const float*)d_in[11];
    const float* Wo  = (const float*)d_in[12];
    const float* bo  = (const float*)d_in[13];

    char* ws = (char*)d_ws;
    bf16*  Xbf  = (bf16*)(ws);                          // 64 MiB; later KT
    bf16*  QT   = (bf16*)(ws + (size_t) 67108864);      // 64 MiB [b][ch][l]
    bf16*  XS   = (bf16*)(ws + (size_t)134217728);      // 64 MiB; later F
    bf16*  VB   = (bf16*)(ws + (size_t)201326592);      // 64 MiB
    bf16*  Pbuf = (bf16*)(ws + (size_t)268435456);      // 2 MiB
    bf16*  wslot= (bf16*)(ws + (size_t)270532608);      // 2 MiB
    float* posb = (float*)(ws + (size_t)272629760);     // 512 KiB
    float* weff = (float*)(ws + (size_t)273154048);
    float* wcst = (float*)(ws + (size_t)273159168);
    bf16*  KT = Xbf;     // Xbf dead after sample_kernel
    bf16*  Fb = XS;      // XS dead after K/V GEMMs

    prep_weff_kernel<<<dim3(KW), dim3(GCH), 0, stream>>>(W1, b1, w2, b2, weff, wcst);
    cvt_kernel<<<dim3(MROWS*CH/8/256), 256, 0, stream>>>(x, Xbf, MROWS*CH);

    cvt_kernel<<<dim3(CH*CH/8/256), 256, 0, stream>>>(Wq, wslot, CH*CH);
    gemm256_kernel<2><<<dim3(512), 512, 0, stream>>>(Xbf, wslot, bq, nullptr, QT);

    offsets_kernel<<<dim3(SEQ/256, NBG), 256, 0, stream>>>(QT, weff, wcst, posb);
    sample_kernel<<<dim3(SEQ/8, NBG), 256, 0, stream>>>(Xbf, posb, XS);

    cvt_kernel<<<dim3(CH*CH/8/256), 256, 0, stream>>>(Wk, wslot, CH*CH);
    gemm256_kernel<2><<<dim3(512), 512, 0, stream>>>(XS, wslot, bk, nullptr, KT);

    cvt_kernel<<<dim3(CH*CH/8/256), 256, 0, stream>>>(Wv, wslot, CH*CH);
    gemm256_kernel<1><<<dim3(512), 512, 0, stream>>>(XS, wslot, bv, rpb, VB);

    attn_s_kernel<<<dim3(NBH), 256, 0, stream>>>(QT, KT, Pbuf);
    attn_pv_kernel<<<dim3(8, NBH), 256, 0, stream>>>(Pbuf, VB, Fb);

    cvt_kernel<<<dim3(CH*CH/8/256), 256, 0, stream>>>(Wo, wslot, CH*CH);
    gemm256_kernel<3><<<dim3(512), 512, 0, stream>>>(Fb, wslot, bo, nullptr, (float*)d_out);
}